// Round 10
// baseline (101.959 us; speedup 1.0000x reference)
//
#include <hip/hip_runtime.h>
#include <hip/hip_bf16.h>

#define NB 16
#define DIM 256
#define HW 4096
#define HEADS 4
#define DHEAD 32
#define MEM 4
#define HIDDEN 128

typedef __hip_bfloat16 bf16;
typedef __attribute__((ext_vector_type(8))) short bf16x8;
typedef __attribute__((ext_vector_type(4))) float f32x4;
typedef __attribute__((ext_vector_type(4))) unsigned short us4;

#define AS1 __attribute__((address_space(1)))
#define AS3 __attribute__((address_space(3)))

__device__ __forceinline__ void gld_lds16(const void* g, void* l) {
    __builtin_amdgcn_global_load_lds((const AS1 void*)g, (AS3 void*)l, 16, 0, 0);
}
__device__ __forceinline__ float b2f(short s) {
    union { unsigned int u; float f; } x; x.u = ((unsigned int)(unsigned short)s) << 16; return x.f;
}
__device__ __forceinline__ short f2bs(float f) {
    bf16 h = __float2bfloat16(f);
    return *reinterpret_cast<short*>(&h);
}

// ---- ws layout (bytes) ----
constexpr size_t OFF_W1B  = 0;                                    // 384*256 bf16
constexpr size_t OFF_RP   = OFF_W1B + 98304*2;                    // 4*65536 f32
constexpr size_t OFF_PCTX = OFF_RP + 4*65536*4;                   // 64*64*1056 f32 = 17.3MB
constexpr size_t OFF_CTXN = OFF_PCTX + (size_t)64*64*1056*4;      // 64*1024 f32
constexpr size_t OFF_M    = OFF_CTXN + (size_t)64*1024*4;         // 16*256*128 bf16
constexpr size_t OFF_QT   = OFF_M + (size_t)NB*DIM*HIDDEN*2;      // 16*4096*128 bf16
constexpr size_t OFF_XT   = OFF_QT + (size_t)NB*HW*HIDDEN*2;      // 16*4096*256 bf16

// K1: w1b = bf16(w_qkv * g1)
__global__ void k_prep(const float* __restrict__ wqkv, const float* __restrict__ g1,
                       short* __restrict__ w1b) {
    int i = blockIdx.x * 256 + threadIdx.x;
    w1b[i] = f2bs(wqkv[i] * g1[i & (DIM - 1)]);
}

// K2: transpose x -> xT[b][n][c] (bf16) + partial sumsq per (b,n) (~HBM floor)
__global__ __launch_bounds__(256) void k_tr(const float* __restrict__ x,
                                            short* __restrict__ xT,
                                            float* __restrict__ rpart) {
    int n0 = blockIdx.x * 64, cy = blockIdx.y, b = blockIdx.z;
    int c0 = cy * 64;
    __shared__ short xs[64 * 65];
    __shared__ float ps[4][64];
    int t = threadIdx.x;
    int ln = t & 63, cb = t >> 6;
    const float* xp = x + ((size_t)b * DIM + c0) * HW + n0;
    float ss = 0.f;
#pragma unroll
    for (int j = 0; j < 16; ++j) {
        int c = cb * 16 + j;
        float v = xp[(size_t)c * HW + ln];
        ss += v * v;
        xs[c * 65 + ln] = f2bs(v);
    }
    ps[cb][ln] = ss;
    __syncthreads();
    if (t < 64)
        rpart[((size_t)cy * NB + b) * HW + n0 + t] = ps[0][t] + ps[1][t] + ps[2][t] + ps[3][t];
    int n = t >> 2, ch = t & 3;
    alignas(16) short tmp[16];
#pragma unroll
    for (int i = 0; i < 16; ++i) tmp[i] = xs[(ch * 16 + i) * 65 + n];
    short* o = xT + ((size_t)b * HW + n0 + n) * DIM + c0 + ch * 16;
    *(bf16x8*)(o)     = *(bf16x8*)(tmp);
    *(bf16x8*)(o + 8) = *(bf16x8*)(tmp + 8);
}

// K3: GEMM (BM=384, BN=64, 6 waves). A (w1b rows) in REGISTERS direct from L2-hot
// global; full-K 32KB B-panel staged ONCE (XOR-swizzled). ONE barrier before the
// MFMA phase, zero barriers inside. r folded from rpart. Epilogue (R7-proven):
// q-softmax -> qT; k,v -> exp/scale -> LDS tiles -> PV MFMA -> pctx (+rowsum).
__global__ __launch_bounds__(384, 3) void k_gemm(const short* __restrict__ w1b,
                                                 const short* __restrict__ xT,
                                                 const float* __restrict__ rpart,
                                                 short* __restrict__ qT,
                                                 float* __restrict__ pctx) {
    __shared__ __align__(16) char smem[33280];  // Bs 32KB (-> ekb/vb) | r2s 256B @32768
    float* r2s = (float*)(smem + 32768);
    int nt = blockIdx.x, b = blockIdx.y;
    int n0g = nt * 64;
    int t = threadIdx.x;
    int w = t >> 6, lane = t & 63;
    int lr = lane & 15, lg = lane >> 4;
    const f32x4 fz = {0.f, 0.f, 0.f, 0.f};
    f32x4 acc[4][4];
#pragma unroll
    for (int m = 0; m < 4; ++m)
#pragma unroll
        for (int n = 0; n < 4; ++n) acc[m][n] = fz;

    // stage full-K B-panel: 64 rows x 256 k bf16 = 32KB, linear dest + pre-swizzled src
    const short* Bg = xT + ((size_t)b * HW + n0g) * 256;
#pragma unroll
    for (int is = 0; is < 5; ++is) {
        int o = is * 6144 + t * 16;
        int row = o >> 9;                        // 512B per row
        int js = ((o >> 4) & 31) ^ (row & 31);
        gld_lds16(Bg + (size_t)row * 256 + js * 8, smem + o);
    }
    if (t < 128) {
        int o = 30720 + t * 16;
        int row = o >> 9;
        int js = ((o >> 4) & 31) ^ (row & 31);
        gld_lds16(Bg + (size_t)row * 256 + js * 8, smem + o);
    }
    // r for this block's 64 columns (k_rfin folded)
    if (t < 64) {
        int col = n0g + t;
        float s = rpart[(size_t)b * HW + col] + rpart[(size_t)(16 + b) * HW + col]
                + rpart[(size_t)(32 + b) * HW + col] + rpart[(size_t)(48 + b) * HW + col];
        r2s[t] = 16.0f / fmaxf(sqrtf(s), 1e-12f);
    }
    // A first K-half into registers (overlaps B staging; w1b is L2-hot)
    const short* Ag = w1b + (size_t)(w * 64 + lr) * 256 + lg * 8;
    bf16x8 a1[4][4];
#pragma unroll
    for (int m = 0; m < 4; ++m)
#pragma unroll
        for (int kc = 0; kc < 4; ++kc)
            a1[m][kc] = *(const bf16x8*)(Ag + (size_t)m * 16 * 256 + kc * 32);
    __syncthreads();

    // phase 1: K 0..127, zero barriers
#pragma unroll
    for (int kc = 0; kc < 4; ++kc) {
        bf16x8 bv[4];
#pragma unroll
        for (int nf = 0; nf < 4; ++nf) {
            int row = nf * 16 + lr;
            int phys = (kc * 4 + lg) ^ (row & 31);
            bv[nf] = *(const bf16x8*)(smem + row * 512 + phys * 16);
        }
#pragma unroll
        for (int m = 0; m < 4; ++m)
#pragma unroll
            for (int nf = 0; nf < 4; ++nf)
                acc[m][nf] = __builtin_amdgcn_mfma_f32_16x16x32_bf16(a1[m][kc], bv[nf], acc[m][nf], 0, 0, 0);
    }
    // A second K-half
    bf16x8 a2[4][4];
#pragma unroll
    for (int m = 0; m < 4; ++m)
#pragma unroll
        for (int kc = 0; kc < 4; ++kc)
            a2[m][kc] = *(const bf16x8*)(Ag + (size_t)m * 16 * 256 + 128 + kc * 32);
    // phase 2: K 128..255
#pragma unroll
    for (int kc = 0; kc < 4; ++kc) {
        bf16x8 bv[4];
#pragma unroll
        for (int nf = 0; nf < 4; ++nf) {
            int row = nf * 16 + lr;
            int phys = ((kc + 4) * 4 + lg) ^ (row & 31);
            bv[nf] = *(const bf16x8*)(smem + row * 512 + phys * 16);
        }
#pragma unroll
        for (int m = 0; m < 4; ++m)
#pragma unroll
            for (int nf = 0; nf < 4; ++nf)
                acc[m][nf] = __builtin_amdgcn_mfma_f32_16x16x32_bf16(a2[m][kc], bv[nf], acc[m][nf], 0, 0, 0);
    }

    float rv[4];
#pragma unroll
    for (int nf = 0; nf < 4; ++nf) rv[nf] = r2s[nf * 16 + lr];

    __syncthreads();                        // MFMA LDS reads done; reuse Bs region
    short* ekb = (short*)smem;              // [128][64] bf16
    short* vb  = (short*)(smem + 16384);    // [128][64] bf16

    if (w < 2) {
        // q: softmax over d (32 rows/head); heads h = w*2+a  (R7-proven)
#pragma unroll
        for (int nf = 0; nf < 4; ++nf) {
            int gcol = n0g + nf * 16 + lr;
#pragma unroll
            for (int a = 0; a < 2; ++a) {
                float v[8];
#pragma unroll
                for (int mm = 0; mm < 2; ++mm)
#pragma unroll
                    for (int q = 0; q < 4; ++q)
                        v[mm * 4 + q] = acc[2 * a + mm][nf][q] * rv[nf];
                float mx = v[0];
#pragma unroll
                for (int i = 1; i < 8; ++i) mx = fmaxf(mx, v[i]);
                mx = fmaxf(mx, __shfl_xor(mx, 16));
                mx = fmaxf(mx, __shfl_xor(mx, 32));
                float sum = 0.f;
#pragma unroll
                for (int i = 0; i < 8; ++i) { v[i] = __expf(v[i] - mx); sum += v[i]; }
                sum += __shfl_xor(sum, 16);
                sum += __shfl_xor(sum, 32);
                float inv = 0.17677669529663689f / sum;   // dhead^-0.5 / sum
                size_t base = ((size_t)b * HW + gcol) * 128 + (w * 2 + a) * 32 + lg * 4;
#pragma unroll
                for (int mm = 0; mm < 2; ++mm) {
                    us4 pk;
#pragma unroll
                    for (int q = 0; q < 4; ++q)
                        pk[q] = (unsigned short)f2bs(v[mm * 4 + q] * inv);
                    *(us4*)(qT + base + mm * 16) = pk;
                }
            }
        }
    } else if (w < 4) {
        // k rows: ek = exp(k*r) -> bf16 tile
#pragma unroll
        for (int m = 0; m < 4; ++m)
#pragma unroll
            for (int nf = 0; nf < 4; ++nf)
#pragma unroll
                for (int q = 0; q < 4; ++q) {
                    int rloc = (w - 2) * 64 + m * 16 + lg * 4 + q;
                    ekb[rloc * 64 + nf * 16 + lr] = f2bs(__expf(acc[m][nf][q] * rv[nf]));
                }
    } else {
        // v rows -> bf16 tile
#pragma unroll
        for (int m = 0; m < 4; ++m)
#pragma unroll
            for (int nf = 0; nf < 4; ++nf)
#pragma unroll
                for (int q = 0; q < 4; ++q) {
                    int rloc = (w - 4) * 64 + m * 16 + lg * 4 + q;
                    vb[rloc * 64 + nf * 16 + lr] = f2bs(acc[m][nf][q] * rv[nf]);
                }
    }
    __syncthreads();
    if (w < 4) {
        // PV MFMA: ctx_h[d][e] = sum_n ek[d][n]*v[e][n]; wave w = head h
        int h = w;
        f32x4 c2[2][2];
        c2[0][0] = fz; c2[0][1] = fz; c2[1][0] = fz; c2[1][1] = fz;
#pragma unroll
        for (int ks = 0; ks < 2; ++ks) {
            int j = lg + 4 * ks;
            bf16x8 a2b[2], b2[2];
#pragma unroll
            for (int mm = 0; mm < 2; ++mm)
                a2b[mm] = *(const bf16x8*)(ekb + (h * 32 + mm * 16 + lr) * 64 + j * 8);
#pragma unroll
            for (int nn = 0; nn < 2; ++nn)
                b2[nn] = *(const bf16x8*)(vb + (h * 32 + nn * 16 + lr) * 64 + j * 8);
#pragma unroll
            for (int mm = 0; mm < 2; ++mm)
#pragma unroll
                for (int nn = 0; nn < 2; ++nn)
                    c2[mm][nn] = __builtin_amdgcn_mfma_f32_16x16x32_bf16(a2b[mm], b2[nn], c2[mm][nn], 0, 0, 0);
        }
        float* o = pctx + ((size_t)nt * 64 + b * 4 + h) * 1056;
#pragma unroll
        for (int mm = 0; mm < 2; ++mm)
#pragma unroll
            for (int nn = 0; nn < 2; ++nn)
#pragma unroll
                for (int qq = 0; qq < 4; ++qq) {
                    int d = mm * 16 + lg * 4 + qq;
                    int e = nn * 16 + lr;
                    o[d * 32 + e] = c2[mm][nn][qq];
                }
    } else {
        // rowsum partials from the same bf16 ek values
        int hd = (w - 4) * 64 + lane;
        float rs = 0.f;
#pragma unroll
        for (int blk = 0; blk < 8; ++blk) {
            bf16x8 e8 = *(const bf16x8*)(ekb + hd * 64 + blk * 8);
#pragma unroll
            for (int j = 0; j < 8; ++j) rs += b2f(e8[j]);
        }
        pctx[((size_t)nt * 64 + b * 4 + (hd >> 5)) * 1056 + 1024 + (hd & 31)] = rs;
    }
}

// K4: reduce pctx over 64 chunks + mem-KV terms + normalize -> ctxn[bh][d*32+e]
__global__ __launch_bounds__(256) void k_red(const float* __restrict__ pctx,
                                             const float* __restrict__ memkv,
                                             float* __restrict__ ctxn) {
    int ds = blockIdx.x, bh = blockIdx.y;
    int t = threadIdx.x;
    int dd = t >> 5, ee = t & 31;
    int d = ds * 8 + dd;
    int h = bh & 3;
    __shared__ float rss[8];
    float s = 0.f;
#pragma unroll 8
    for (int c = 0; c < 64; ++c)
        s += pctx[((size_t)c * 64 + bh) * 1056 + d * 32 + ee];
    if (t < 8) {
        int d2 = ds * 8 + t;
        float rs = 0.f;
#pragma unroll 8
        for (int c = 0; c < 64; ++c)
            rs += pctx[((size_t)c * 64 + bh) * 1056 + 1024 + d2];
#pragma unroll
        for (int m2 = 0; m2 < MEM; ++m2) rs += __expf(memkv[(h * 32 + d2) * MEM + m2]);
        rss[t] = rs;
    }
    float mem = 0.f;
#pragma unroll
    for (int m2 = 0; m2 < MEM; ++m2)
        mem += __expf(memkv[(h * 32 + d) * MEM + m2]) * memkv[512 + (h * 32 + ee) * MEM + m2];
    __syncthreads();
    ctxn[(size_t)bh * 1024 + d * 32 + ee] = (s + mem) / rss[dd];
}

// K5: fold w_out: Mmat[b][o][hd] = sum_e wout[o][h*32+e] * ctxn[b*4+h][d][e]
__global__ __launch_bounds__(256) void k_M2(const float* __restrict__ ctxn,
                                            const float* __restrict__ wout,
                                            short* __restrict__ Mmat) {
    int og = blockIdx.x, b = blockIdx.y;
    __shared__ float ctx[4 * 33 * 33];
    __shared__ float wsw[32 * 136];
    int t = threadIdx.x;
#pragma unroll
    for (int j = 0; j < 16; ++j) {
        int e = t + j * 256;
        int h = e >> 10, dd = (e >> 5) & 31, ee = e & 31;
        ctx[h * 1089 + dd * 33 + ee] = ctxn[(size_t)(b * 4 + h) * 1024 + (e & 1023)];
    }
#pragma unroll
    for (int j = 0; j < 4; ++j) {
        int e4 = t + j * 256;
        int row = e4 >> 5, c = (e4 & 31) * 4;
        f32x4 w4 = *(const f32x4*)(wout + (size_t)(og * 32 + row) * HIDDEN + c);
        *(f32x4*)(wsw + row * 136 + (c >> 5) * 34 + (c & 31)) = w4;
    }
    __syncthreads();
    int ol = t >> 3, hg = t & 7;
    alignas(16) short out16[16];
#pragma unroll
    for (int ii = 0; ii < 16; ++ii) {
        int hd = hg * 16 + ii;
        int h = hd >> 5, dd = hd & 31;
        float s = 0.f;
#pragma unroll
        for (int e = 0; e < 32; ++e)
            s += wsw[ol * 136 + h * 34 + e] * ctx[h * 1089 + dd * 33 + e];
        out16[ii] = f2bs(s);
    }
    short* op = Mmat + ((size_t)(b * 256 + og * 32 + ol)) * 128 + hg * 16;
    *(bf16x8*)(op)     = *(bf16x8*)(out16);
    *(bf16x8*)(op + 8) = *(bf16x8*)(out16 + 8);
}

// K6: fused final GEMM + bias + column RMS-norm + g2 scale -> f32 out
__global__ __launch_bounds__(256) void k_out2(const short* __restrict__ Mmat,
                                              const short* __restrict__ qT,
                                              const float* __restrict__ bout,
                                              const float* __restrict__ g2,
                                              float* __restrict__ out) {
    int nt = blockIdx.x, b = blockIdx.y;
    __shared__ short As[256 * 64];
    __shared__ short Bs[64 * 64];
    __shared__ float sw[4][80];
    __shared__ float r2s[64];
    int t = threadIdx.x;
    int wave = t >> 6, lane = t & 63;
    int lr = lane & 15, lg = lane >> 4;
    const short* Ag = Mmat + (size_t)b * 256 * 128;
    const short* Bg = qT + ((size_t)b * HW + nt * 64) * 128;
    const f32x4 fz = {0.f, 0.f, 0.f, 0.f};
    f32x4 acc[4][4];
#pragma unroll
    for (int m = 0; m < 4; ++m)
#pragma unroll
        for (int n = 0; n < 4; ++n) acc[m][n] = fz;

    for (int kk = 0; kk < 128; kk += 64) {
        if (kk) __syncthreads();
#pragma unroll
        for (int is = 0; is < 8; ++is) {
            int o = is * 4096 + t * 16;
            int rr2 = o >> 7;
            int js = ((o >> 4) & 7) ^ (rr2 & 7);
            gld_lds16(Ag + (size_t)rr2 * 128 + kk + js * 8, (char*)As + o);
        }
#pragma unroll
        for (int is = 0; is < 2; ++is) {
            int o = is * 4096 + t * 16;
            int rr2 = o >> 7;
            int js = ((o >> 4) & 7) ^ (rr2 & 7);
            gld_lds16(Bg + (size_t)rr2 * 128 + kk + js * 8, (char*)Bs + o);
        }
        __syncthreads();
#pragma unroll
        for (int ks = 0; ks < 2; ++ks) {
            bf16x8 av[4], bv[4];
            int j = lg + 4 * ks;
#pragma unroll
            for (int m = 0; m < 4; ++m) {
                int row = wave * 64 + m * 16 + lr;
                av[m] = *(const bf16x8*)((const char*)As + row * 128 + ((j ^ (row & 7)) << 4));
            }
#pragma unroll
            for (int n = 0; n < 4; ++n) {
                int row = n * 16 + lr;
                bv[n] = *(const bf16x8*)((const char*)Bs + row * 128 + ((j ^ (row & 7)) << 4));
            }
#pragma unroll
            for (int m = 0; m < 4; ++m)
#pragma unroll
                for (int n = 0; n < 4; ++n)
                    acc[m][n] = __builtin_amdgcn_mfma_f32_16x16x32_bf16(av[m], bv[n], acc[m][n], 0, 0, 0);
        }
    }
    float bb[4][4], gg[4][4];
#pragma unroll
    for (int m = 0; m < 4; ++m)
#pragma unroll
        for (int q = 0; q < 4; ++q) {
            int row = wave * 64 + m * 16 + lg * 4 + q;
            bb[m][q] = bout[row];
            gg[m][q] = g2[row];
        }
    float ssn[4] = {0.f, 0.f, 0.f, 0.f};
#pragma unroll
    for (int n = 0; n < 4; ++n)
#pragma unroll
        for (int m = 0; m < 4; ++m)
#pragma unroll
            for (int q = 0; q < 4; ++q) {
                float val = acc[m][n][q] + bb[m][q];
                acc[m][n][q] = val;
                ssn[n] += val * val;
            }
#pragma unroll
    for (int n = 0; n < 4; ++n) {
        ssn[n] += __shfl_xor(ssn[n], 16);
        ssn[n] += __shfl_xor(ssn[n], 32);
    }
    if (lg == 0) {
#pragma unroll
        for (int n = 0; n < 4; ++n) sw[wave][n * 16 + lr] = ssn[n];
    }
    __syncthreads();
    if (t < 64) {
        float s = sw[0][t] + sw[1][t] + sw[2][t] + sw[3][t];
        r2s[t] = 16.0f / fmaxf(sqrtf(s), 1e-12f);
    }
    __syncthreads();
    float* op = out + (size_t)b * DIM * HW + nt * 64;
#pragma unroll
    for (int n = 0; n < 4; ++n) {
        float rc = r2s[n * 16 + lr];
#pragma unroll
        for (int m = 0; m < 4; ++m)
#pragma unroll
            for (int q = 0; q < 4; ++q) {
                int row = wave * 64 + m * 16 + lg * 4 + q;
                op[(size_t)row * HW + n * 16 + lr] = acc[m][n][q] * rc * gg[m][q];
            }
    }
}

extern "C" void kernel_launch(void* const* d_in, const int* in_sizes, int n_in,
                              void* d_out, int out_size, void* d_ws, size_t ws_size,
                              hipStream_t stream) {
    const float* x     = (const float*)d_in[0];
    const float* g1    = (const float*)d_in[1];
    const float* wqkv  = (const float*)d_in[2];
    const float* memkv = (const float*)d_in[3];
    const float* wout  = (const float*)d_in[4];
    const float* bout  = (const float*)d_in[5];
    const float* g2    = (const float*)d_in[6];
    float* out = (float*)d_out;
    char* ws = (char*)d_ws;

    short* w1b  = (short*)(ws + OFF_W1B);
    float* rpart= (float*)(ws + OFF_RP);
    float* pctx = (float*)(ws + OFF_PCTX);
    float* ctxn = (float*)(ws + OFF_CTXN);
    short* Mmat = (short*)(ws + OFF_M);
    short* qT   = (short*)(ws + OFF_QT);
    short* xT   = (short*)(ws + OFF_XT);

    k_prep<<<384, 256, 0, stream>>>(wqkv, g1, w1b);
    k_tr<<<dim3(64, 4, NB), 256, 0, stream>>>(x, xT, rpart);
    k_gemm<<<dim3(64, NB), 384, 0, stream>>>(w1b, xT, rpart, qT, pctx);
    k_red<<<dim3(4, 64), 256, 0, stream>>>(pctx, memkv, ctxn);
    k_M2<<<dim3(8, NB), 256, 0, stream>>>(ctxn, wout, Mmat);
    k_out2<<<dim3(64, NB), 256, 0, stream>>>(Mmat, qT, bout, g2, out);
}

// Round 11
// 78.089 us; speedup vs baseline: 1.3057x; 1.3057x over previous
//
#include <hip/hip_runtime.h>
#include <hip/hip_bf16.h>

#define NB 16
#define DIM 256
#define HW 4096
#define HEADS 4
#define DHEAD 32
#define MEM 4
#define HIDDEN 128

typedef __hip_bfloat16 bf16;
typedef __attribute__((ext_vector_type(8))) short bf16x8;
typedef __attribute__((ext_vector_type(4))) float f32x4;
typedef __attribute__((ext_vector_type(4))) unsigned short us4;

#define AS1 __attribute__((address_space(1)))
#define AS3 __attribute__((address_space(3)))

__device__ __forceinline__ void gld_lds16(const void* g, void* l) {
    __builtin_amdgcn_global_load_lds((const AS1 void*)g, (AS3 void*)l, 16, 0, 0);
}
__device__ __forceinline__ float b2f(short s) {
    union { unsigned int u; float f; } x; x.u = ((unsigned int)(unsigned short)s) << 16; return x.f;
}
__device__ __forceinline__ short f2bs(float f) {
    bf16 h = __float2bfloat16(f);
    return *reinterpret_cast<short*>(&h);
}

// ---- ws layout (bytes) ----
constexpr size_t OFF_W1B  = 0;                                    // 384*256 bf16
constexpr size_t OFF_RP   = OFF_W1B + 98304*2;                    // 4*65536 f32
constexpr size_t OFF_PCTX = OFF_RP + 4*65536*4;                   // 32*64*1056 f32
constexpr size_t OFF_CTXN = OFF_PCTX + (size_t)32*64*1056*4;      // 64*1024 f32
constexpr size_t OFF_M    = OFF_CTXN + (size_t)64*1024*4;         // 16*256*128 bf16
constexpr size_t OFF_QT   = OFF_M + (size_t)NB*DIM*HIDDEN*2;      // 16*4096*128 bf16
constexpr size_t OFF_XT   = OFF_QT + (size_t)NB*HW*HIDDEN*2;      // 16*4096*256 bf16

// K1: w1b = bf16(w_qkv * g1)
__global__ void k_prep(const float* __restrict__ wqkv, const float* __restrict__ g1,
                       short* __restrict__ w1b) {
    int i = blockIdx.x * 256 + threadIdx.x;
    w1b[i] = f2bs(wqkv[i] * g1[i & (DIM - 1)]);
}

// K2: transpose x -> xT[b][n][c] (bf16) + partial sumsq per (b,n) (~HBM floor)
__global__ __launch_bounds__(256) void k_tr(const float* __restrict__ x,
                                            short* __restrict__ xT,
                                            float* __restrict__ rpart) {
    int n0 = blockIdx.x * 64, cy = blockIdx.y, b = blockIdx.z;
    int c0 = cy * 64;
    __shared__ short xs[64 * 65];
    __shared__ float ps[4][64];
    int t = threadIdx.x;
    int ln = t & 63, cb = t >> 6;
    const float* xp = x + ((size_t)b * DIM + c0) * HW + n0;
    float ss = 0.f;
#pragma unroll
    for (int j = 0; j < 16; ++j) {
        int c = cb * 16 + j;
        float v = xp[(size_t)c * HW + ln];
        ss += v * v;
        xs[c * 65 + ln] = f2bs(v);
    }
    ps[cb][ln] = ss;
    __syncthreads();
    if (t < 64)
        rpart[((size_t)cy * NB + b) * HW + n0 + t] = ps[0][t] + ps[1][t] + ps[2][t] + ps[3][t];
    int n = t >> 2, ch = t & 3;
    alignas(16) short tmp[16];
#pragma unroll
    for (int i = 0; i < 16; ++i) tmp[i] = xs[(ch * 16 + i) * 65 + n];
    short* o = xT + ((size_t)b * HW + n0 + n) * DIM + c0 + ch * 16;
    *(bf16x8*)(o)     = *(bf16x8*)(tmp);
    *(bf16x8*)(o + 8) = *(bf16x8*)(tmp + 8);
}

// K3: GEMM (BM=384, BN=128, 12 waves) with T3-minimum 2-phase counted pipeline:
//  double-buffered As/Bs (128KB dynamic LDS). Per K-step:
//    STAGE(next,buf^1) -> setprio(1) MFMA(cur,buf) setprio(0) -> vmcnt(0) -> raw barrier.
//  No compiler drain before MFMAs; stage latency hides under the MFMA phase.
//  Epilogue (R8-proven, 0 conflicts): q-softmax -> qT; k,v -> exp/scale -> swizzled
//  LDS tiles -> PV MFMA -> pctx partials (+rowsum). r folded from rpart per-thread.
__global__ __launch_bounds__(768, 1) void k_gemm(const short* __restrict__ w1b,
                                                 const short* __restrict__ xT,
                                                 const float* __restrict__ rpart,
                                                 short* __restrict__ qT,
                                                 float* __restrict__ pctx) {
    extern __shared__ __align__(16) char smem[];
    // As dbuf @0 / @49152 (48KB each); Bs dbuf @98304 / @114688 (16KB each). 128KB total.
    int nt = blockIdx.x, b = blockIdx.y;
    int t = threadIdx.x;
    int w = t >> 6, lane = t & 63;
    int wr = w >> 1, wc = w & 1;
    int lr = lane & 15, lg = lane >> 4;
    const f32x4 fz = {0.f, 0.f, 0.f, 0.f};
    f32x4 acc[4][4];
#pragma unroll
    for (int m = 0; m < 4; ++m)
#pragma unroll
        for (int n = 0; n < 4; ++n) acc[m][n] = fz;

    const short* Bg = xT + ((size_t)b * HW + nt * 128) * 256;

    auto STAGE = [&](int kt, int buf) {
        int kk = kt * 64;
        char* asb = smem + buf * 49152;
        char* bsb = smem + 98304 + buf * 16384;
#pragma unroll
        for (int is = 0; is < 4; ++is) {          // As: 384x64 bf16 = 48KB
            int o = is * 12288 + t * 16;
            int row = o >> 7;                     // 128B rows
            int js = ((o >> 4) & 7) ^ (row & 7);  // pre-swizzled source (T2)
            gld_lds16(w1b + (size_t)row * 256 + kk + js * 8, asb + o);
        }
        {                                          // Bs: 128x64 bf16 = 16KB
            int o = t * 16;
            int row = o >> 7;
            int js = ((o >> 4) & 7) ^ (row & 7);
            gld_lds16(Bg + (size_t)row * 256 + kk + js * 8, bsb + o);
        }
        if (t < 256) {
            int o = 12288 + t * 16;
            int row = o >> 7;
            int js = ((o >> 4) & 7) ^ (row & 7);
            gld_lds16(Bg + (size_t)row * 256 + kk + js * 8, bsb + o);
        }
    };

    // prologue
    STAGE(0, 0);
    asm volatile("s_waitcnt vmcnt(0)" ::: "memory");
    __builtin_amdgcn_s_barrier();

#pragma unroll
    for (int kt = 0; kt < 4; ++kt) {
        int buf = kt & 1;
        if (kt < 3) STAGE(kt + 1, buf ^ 1);       // issue-early (T14)
        const char* asb = smem + buf * 49152;
        const char* bsb = smem + 98304 + buf * 16384;
        __builtin_amdgcn_s_setprio(1);
#pragma unroll
        for (int ks = 0; ks < 2; ++ks) {
            int j = lg + 4 * ks;
            bf16x8 av[4], bv[4];
#pragma unroll
            for (int m = 0; m < 4; ++m) {
                int row = wr * 64 + m * 16 + lr;
                av[m] = *(const bf16x8*)(asb + row * 128 + ((j ^ (row & 7)) << 4));
            }
#pragma unroll
            for (int nf = 0; nf < 4; ++nf) {
                int row = wc * 64 + nf * 16 + lr;
                bv[nf] = *(const bf16x8*)(bsb + row * 128 + ((j ^ (row & 7)) << 4));
            }
#pragma unroll
            for (int m = 0; m < 4; ++m)
#pragma unroll
                for (int nf = 0; nf < 4; ++nf)
                    acc[m][nf] = __builtin_amdgcn_mfma_f32_16x16x32_bf16(av[m], bv[nf], acc[m][nf], 0, 0, 0);
        }
        __builtin_amdgcn_s_setprio(0);
        asm volatile("s_waitcnt vmcnt(0)" ::: "memory");   // counted drain: only next-tile loads
        __builtin_amdgcn_s_barrier();
    }

    // r for this thread's 4 columns (k_rfin folded, per-thread from L2-hot rpart)
    int gcol0 = nt * 128 + wc * 64 + lr;
    float rv[4];
#pragma unroll
    for (int nf = 0; nf < 4; ++nf) {
        int col = gcol0 + nf * 16;
        float s = rpart[(size_t)b * HW + col] + rpart[(size_t)(16 + b) * HW + col]
                + rpart[(size_t)(32 + b) * HW + col] + rpart[(size_t)(48 + b) * HW + col];
        rv[nf] = 16.0f / fmaxf(sqrtf(s), 1e-12f);
    }

    // epilogue: LDS buffers all free (final barrier above)
    short* ekb = (short*)smem;              // [128 kd][128 col] bf16, 16B-chunk XOR swizzle
    short* vb  = (short*)(smem + 32768);    // [128 vd][128 col]

    if (wr < 2) {
        // q rows: softmax over d (32/head); head = wr*2 + a
#pragma unroll
        for (int nf = 0; nf < 4; ++nf) {
            int gcol = gcol0 + nf * 16;
#pragma unroll
            for (int a = 0; a < 2; ++a) {
                float v[8];
#pragma unroll
                for (int mm = 0; mm < 2; ++mm)
#pragma unroll
                    for (int q = 0; q < 4; ++q)
                        v[mm * 4 + q] = acc[2 * a + mm][nf][q] * rv[nf];
                float mx = v[0];
#pragma unroll
                for (int i = 1; i < 8; ++i) mx = fmaxf(mx, v[i]);
                mx = fmaxf(mx, __shfl_xor(mx, 16));
                mx = fmaxf(mx, __shfl_xor(mx, 32));
                float sum = 0.f;
#pragma unroll
                for (int i = 0; i < 8; ++i) { v[i] = __expf(v[i] - mx); sum += v[i]; }
                sum += __shfl_xor(sum, 16);
                sum += __shfl_xor(sum, 32);
                float inv = 0.17677669529663689f / sum;   // dhead^-0.5 / sum
                size_t base = ((size_t)b * HW + gcol) * 128 + (wr * 2 + a) * 32 + lg * 4;
#pragma unroll
                for (int mm = 0; mm < 2; ++mm) {
                    us4 pk;
#pragma unroll
                    for (int q = 0; q < 4; ++q)
                        pk[q] = (unsigned short)f2bs(v[mm * 4 + q] * inv);
                    *(us4*)(qT + base + mm * 16) = pk;
                }
            }
        }
    } else if (wr < 4) {
        // k rows -> ek = exp(k*r), swizzled tile
#pragma unroll
        for (int m = 0; m < 4; ++m)
#pragma unroll
            for (int nf = 0; nf < 4; ++nf)
#pragma unroll
                for (int q = 0; q < 4; ++q) {
                    int rloc = (wr - 2) * 64 + m * 16 + lg * 4 + q;
                    int col = wc * 64 + nf * 16 + lr;
                    int cs = ((((col >> 3) ^ (rloc & 15)) << 3) | (col & 7));
                    ekb[rloc * 128 + cs] = f2bs(__expf(acc[m][nf][q] * rv[nf]));
                }
    } else {
        // v rows -> swizzled tile
#pragma unroll
        for (int m = 0; m < 4; ++m)
#pragma unroll
            for (int nf = 0; nf < 4; ++nf)
#pragma unroll
                for (int q = 0; q < 4; ++q) {
                    int rloc = (wr - 4) * 64 + m * 16 + lg * 4 + q;
                    int col = wc * 64 + nf * 16 + lr;
                    int cs = ((((col >> 3) ^ (rloc & 15)) << 3) | (col & 7));
                    vb[rloc * 128 + cs] = f2bs(acc[m][nf][q] * rv[nf]);
                }
    }
    __syncthreads();
    if (w < 4) {
        // PV MFMA: ctx_h[d][e] = sum_n ek[h*32+d][n]*v[h*32+e][n]; wave w = head h
        int h = w;
        f32x4 c2[2][2];
        c2[0][0] = fz; c2[0][1] = fz; c2[1][0] = fz; c2[1][1] = fz;
#pragma unroll
        for (int ks = 0; ks < 4; ++ks) {
            int j = ks * 4 + lg;                 // 16B chunk 0..15
            bf16x8 a2[2], b2[2];
#pragma unroll
            for (int mm = 0; mm < 2; ++mm) {
                int row = h * 32 + mm * 16 + lr;
                a2[mm] = *(const bf16x8*)(ekb + row * 128 + ((j ^ (row & 15)) << 3));
            }
#pragma unroll
            for (int nn = 0; nn < 2; ++nn) {
                int row = h * 32 + nn * 16 + lr;
                b2[nn] = *(const bf16x8*)(vb + row * 128 + ((j ^ (row & 15)) << 3));
            }
#pragma unroll
            for (int mm = 0; mm < 2; ++mm)
#pragma unroll
                for (int nn = 0; nn < 2; ++nn)
                    c2[mm][nn] = __builtin_amdgcn_mfma_f32_16x16x32_bf16(a2[mm], b2[nn], c2[mm][nn], 0, 0, 0);
        }
        float* o = pctx + ((size_t)nt * 64 + b * 4 + h) * 1056;
#pragma unroll
        for (int mm = 0; mm < 2; ++mm)
#pragma unroll
            for (int nn = 0; nn < 2; ++nn)
#pragma unroll
                for (int qq = 0; qq < 4; ++qq) {
                    int d = mm * 16 + lg * 4 + qq;
                    int e = nn * 16 + lr;
                    o[d * 32 + e] = c2[mm][nn][qq];
                }
    } else if (w >= 8) {
        // rowsum partials over 128 cols of ekb
        int hd = (w - 8) * 32 + (lane & 31);
        int half = lane >> 5;
        float rs = 0.f;
#pragma unroll
        for (int blk = 0; blk < 8; ++blk) {
            int chunk = half * 8 + blk;
            bf16x8 e8 = *(const bf16x8*)(ekb + hd * 128 + ((chunk ^ (hd & 15)) << 3));
#pragma unroll
            for (int jj = 0; jj < 8; ++jj) rs += b2f(e8[jj]);
        }
        rs += __shfl_xor(rs, 32);
        if (lane < 32)
            pctx[((size_t)nt * 64 + b * 4 + (w - 8)) * 1056 + 1024 + (lane & 31)] = rs;
    }
}

// K4: reduce pctx over 32 chunks + mem-KV terms + normalize -> ctxn[bh][d*32+e]
__global__ __launch_bounds__(256) void k_red(const float* __restrict__ pctx,
                                             const float* __restrict__ memkv,
                                             float* __restrict__ ctxn) {
    int ds = blockIdx.x, bh = blockIdx.y;
    int t = threadIdx.x;
    int dd = t >> 5, ee = t & 31;
    int d = ds * 8 + dd;
    int h = bh & 3;
    __shared__ float rss[8];
    float s = 0.f;
#pragma unroll 8
    for (int c = 0; c < 32; ++c)
        s += pctx[((size_t)c * 64 + bh) * 1056 + d * 32 + ee];
    if (t < 8) {
        int d2 = ds * 8 + t;
        float rs = 0.f;
#pragma unroll 8
        for (int c = 0; c < 32; ++c)
            rs += pctx[((size_t)c * 64 + bh) * 1056 + 1024 + d2];
#pragma unroll
        for (int m2 = 0; m2 < MEM; ++m2) rs += __expf(memkv[(h * 32 + d2) * MEM + m2]);
        rss[t] = rs;
    }
    float mem = 0.f;
#pragma unroll
    for (int m2 = 0; m2 < MEM; ++m2)
        mem += __expf(memkv[(h * 32 + d) * MEM + m2]) * memkv[512 + (h * 32 + ee) * MEM + m2];
    __syncthreads();
    ctxn[(size_t)bh * 1024 + d * 32 + ee] = (s + mem) / rss[dd];
}

// K5: fold w_out: Mmat[b][o][hd] = sum_e wout[o][h*32+e] * ctxn[b*4+h][d][e]
__global__ __launch_bounds__(256) void k_M2(const float* __restrict__ ctxn,
                                            const float* __restrict__ wout,
                                            short* __restrict__ Mmat) {
    int og = blockIdx.x, b = blockIdx.y;
    __shared__ float ctx[4 * 33 * 33];
    __shared__ float wsw[32 * 136];
    int t = threadIdx.x;
#pragma unroll
    for (int j = 0; j < 16; ++j) {
        int e = t + j * 256;
        int h = e >> 10, dd = (e >> 5) & 31, ee = e & 31;
        ctx[h * 1089 + dd * 33 + ee] = ctxn[(size_t)(b * 4 + h) * 1024 + (e & 1023)];
    }
#pragma unroll
    for (int j = 0; j < 4; ++j) {
        int e4 = t + j * 256;
        int row = e4 >> 5, c = (e4 & 31) * 4;
        f32x4 w4 = *(const f32x4*)(wout + (size_t)(og * 32 + row) * HIDDEN + c);
        *(f32x4*)(wsw + row * 136 + (c >> 5) * 34 + (c & 31)) = w4;
    }
    __syncthreads();
    int ol = t >> 3, hg = t & 7;
    alignas(16) short out16[16];
#pragma unroll
    for (int ii = 0; ii < 16; ++ii) {
        int hd = hg * 16 + ii;
        int h = hd >> 5, dd = hd & 31;
        float s = 0.f;
#pragma unroll
        for (int e = 0; e < 32; ++e)
            s += wsw[ol * 136 + h * 34 + e] * ctx[h * 1089 + dd * 33 + e];
        out16[ii] = f2bs(s);
    }
    short* op = Mmat + ((size_t)(b * 256 + og * 32 + ol)) * 128 + hg * 16;
    *(bf16x8*)(op)     = *(bf16x8*)(out16);
    *(bf16x8*)(op + 8) = *(bf16x8*)(out16 + 8);
}

// K6: fused final GEMM + bias + column RMS-norm + g2 scale -> f32 out
__global__ __launch_bounds__(256) void k_out2(const short* __restrict__ Mmat,
                                              const short* __restrict__ qT,
                                              const float* __restrict__ bout,
                                              const float* __restrict__ g2,
                                              float* __restrict__ out) {
    int nt = blockIdx.x, b = blockIdx.y;
    __shared__ short As[256 * 64];
    __shared__ short Bs[64 * 64];
    __shared__ float sw[4][80];
    __shared__ float r2s[64];
    int t = threadIdx.x;
    int wave = t >> 6, lane = t & 63;
    int lr = lane & 15, lg = lane >> 4;
    const short* Ag = Mmat + (size_t)b * 256 * 128;
    const short* Bg = qT + ((size_t)b * HW + nt * 64) * 128;
    const f32x4 fz = {0.f, 0.f, 0.f, 0.f};
    f32x4 acc[4][4];
#pragma unroll
    for (int m = 0; m < 4; ++m)
#pragma unroll
        for (int n = 0; n < 4; ++n) acc[m][n] = fz;

    for (int kk = 0; kk < 128; kk += 64) {
        if (kk) __syncthreads();
#pragma unroll
        for (int is = 0; is < 8; ++is) {
            int o = is * 4096 + t * 16;
            int rr2 = o >> 7;
            int js = ((o >> 4) & 7) ^ (rr2 & 7);
            gld_lds16(Ag + (size_t)rr2 * 128 + kk + js * 8, (char*)As + o);
        }
#pragma unroll
        for (int is = 0; is < 2; ++is) {
            int o = is * 4096 + t * 16;
            int rr2 = o >> 7;
            int js = ((o >> 4) & 7) ^ (rr2 & 7);
            gld_lds16(Bg + (size_t)rr2 * 128 + kk + js * 8, (char*)Bs + o);
        }
        __syncthreads();
#pragma unroll
        for (int ks = 0; ks < 2; ++ks) {
            bf16x8 av[4], bv[4];
            int j = lg + 4 * ks;
#pragma unroll
            for (int m = 0; m < 4; ++m) {
                int row = wave * 64 + m * 16 + lr;
                av[m] = *(const bf16x8*)((const char*)As + row * 128 + ((j ^ (row & 7)) << 4));
            }
#pragma unroll
            for (int n = 0; n < 4; ++n) {
                int row = n * 16 + lr;
                bv[n] = *(const bf16x8*)((const char*)Bs + row * 128 + ((j ^ (row & 7)) << 4));
            }
#pragma unroll
            for (int m = 0; m < 4; ++m)
#pragma unroll
                for (int n = 0; n < 4; ++n)
                    acc[m][n] = __builtin_amdgcn_mfma_f32_16x16x32_bf16(av[m], bv[n], acc[m][n], 0, 0, 0);
        }
    }
    float bb[4][4], gg[4][4];
#pragma unroll
    for (int m = 0; m < 4; ++m)
#pragma unroll
        for (int q = 0; q < 4; ++q) {
            int row = wave * 64 + m * 16 + lg * 4 + q;
            bb[m][q] = bout[row];
            gg[m][q] = g2[row];
        }
    float ssn[4] = {0.f, 0.f, 0.f, 0.f};
#pragma unroll
    for (int n = 0; n < 4; ++n)
#pragma unroll
        for (int m = 0; m < 4; ++m)
#pragma unroll
            for (int q = 0; q < 4; ++q) {
                float val = acc[m][n][q] + bb[m][q];
                acc[m][n][q] = val;
                ssn[n] += val * val;
            }
#pragma unroll
    for (int n = 0; n < 4; ++n) {
        ssn[n] += __shfl_xor(ssn[n], 16);
        ssn[n] += __shfl_xor(ssn[n], 32);
    }
    if (lg == 0) {
#pragma unroll
        for (int n = 0; n < 4; ++n) sw[wave][n * 16 + lr] = ssn[n];
    }
    __syncthreads();
    if (t < 64) {
        float s = sw[0][t] + sw[1][t] + sw[2][t] + sw[3][t];
        r2s[t] = 16.0f / fmaxf(sqrtf(s), 1e-12f);
    }
    __syncthreads();
    float* op = out + (size_t)b * DIM * HW + nt * 64;
#pragma unroll
    for (int n = 0; n < 4; ++n) {
        float rc = r2s[n * 16 + lr];
#pragma unroll
        for (int m = 0; m < 4; ++m)
#pragma unroll
            for (int q = 0; q < 4; ++q) {
                int row = wave * 64 + m * 16 + lg * 4 + q;
                op[(size_t)row * HW + n * 16 + lr] = acc[m][n][q] * rc * gg[m][q];
            }
    }
}

extern "C" void kernel_launch(void* const* d_in, const int* in_sizes, int n_in,
                              void* d_out, int out_size, void* d_ws, size_t ws_size,
                              hipStream_t stream) {
    const float* x     = (const float*)d_in[0];
    const float* g1    = (const float*)d_in[1];
    const float* wqkv  = (const float*)d_in[2];
    const float* memkv = (const float*)d_in[3];
    const float* wout  = (const float*)d_in[4];
    const float* bout  = (const float*)d_in[5];
    const float* g2    = (const float*)d_in[6];
    float* out = (float*)d_out;
    char* ws = (char*)d_ws;

    short* w1b  = (short*)(ws + OFF_W1B);
    float* rpart= (float*)(ws + OFF_RP);
    float* pctx = (float*)(ws + OFF_PCTX);
    float* ctxn = (float*)(ws + OFF_CTXN);
    short* Mmat = (short*)(ws + OFF_M);
    short* qT   = (short*)(ws + OFF_QT);
    short* xT   = (short*)(ws + OFF_XT);

    // allow 128KB dynamic LDS for k_gemm (non-stream op; deterministic each call)
    hipFuncSetAttribute((const void*)k_gemm,
                        hipFuncAttributeMaxDynamicSharedMemorySize, 131072);

    k_prep<<<384, 256, 0, stream>>>(wqkv, g1, w1b);
    k_tr<<<dim3(64, 4, NB), 256, 0, stream>>>(x, xT, rpart);
    k_gemm<<<dim3(32, NB), 768, 131072, stream>>>(w1b, xT, rpart, qT, pctx);
    k_red<<<dim3(4, 64), 256, 0, stream>>>(pctx, memkv, ctxn);
    k_M2<<<dim3(8, NB), 256, 0, stream>>>(ctxn, wout, Mmat);
    k_out2<<<dim3(64, NB), 256, 0, stream>>>(Mmat, qT, bout, g2, out);
}

// Round 12
// 75.454 us; speedup vs baseline: 1.3513x; 1.0349x over previous
//
#include <hip/hip_runtime.h>
#include <hip/hip_bf16.h>

#define NB 16
#define DIM 256
#define HW 4096
#define HEADS 4
#define DHEAD 32
#define MEM 4
#define HIDDEN 128

typedef __hip_bfloat16 bf16;
typedef __attribute__((ext_vector_type(8))) short bf16x8;
typedef __attribute__((ext_vector_type(4))) float f32x4;
typedef __attribute__((ext_vector_type(4))) unsigned short us4;

#define AS1 __attribute__((address_space(1)))
#define AS3 __attribute__((address_space(3)))

__device__ __forceinline__ void gld_lds16(const void* g, void* l) {
    __builtin_amdgcn_global_load_lds((const AS1 void*)g, (AS3 void*)l, 16, 0, 0);
}
__device__ __forceinline__ float b2f(short s) {
    union { unsigned int u; float f; } x; x.u = ((unsigned int)(unsigned short)s) << 16; return x.f;
}
__device__ __forceinline__ short f2bs(float f) {
    bf16 h = __float2bfloat16(f);
    return *reinterpret_cast<short*>(&h);
}

// ---- ws layout (bytes) ----
constexpr size_t OFF_W1B  = 0;                                    // 384*256 bf16
constexpr size_t OFF_RP   = OFF_W1B + 98304*2;                    // 4*65536 f32
constexpr size_t OFF_PCTX = OFF_RP + 4*65536*4;                   // 32*64*1056 f32
constexpr size_t OFF_CTXN = OFF_PCTX + (size_t)32*64*1056*4;      // 64*1024 f32
constexpr size_t OFF_M    = OFF_CTXN + (size_t)64*1024*4;         // 16*256*128 bf16
constexpr size_t OFF_QT   = OFF_M + (size_t)NB*DIM*HIDDEN*2;      // 16*4096*128 bf16
constexpr size_t OFF_XT   = OFF_QT + (size_t)NB*HW*HIDDEN*2;      // 16*4096*256 bf16

// K1: transpose x -> xT[b][n][c] (bf16) + partial sumsq per (b,n) (~HBM floor).
//     First 384 blocks additionally produce w1b = bf16(w_qkv * g1) (k_prep folded).
__global__ __launch_bounds__(256) void k_tr(const float* __restrict__ x,
                                            const float* __restrict__ wqkv,
                                            const float* __restrict__ g1,
                                            short* __restrict__ xT,
                                            float* __restrict__ rpart,
                                            short* __restrict__ w1b) {
    int t = threadIdx.x;
    int fid = blockIdx.x + (blockIdx.y << 6) + (blockIdx.z << 8);
    if (fid < 384) {
        int i = fid * 256 + t;
        w1b[i] = f2bs(wqkv[i] * g1[i & (DIM - 1)]);
    }
    int n0 = blockIdx.x * 64, cy = blockIdx.y, b = blockIdx.z;
    int c0 = cy * 64;
    __shared__ short xs[64 * 65];
    __shared__ float ps[4][64];
    int ln = t & 63, cb = t >> 6;
    const float* xp = x + ((size_t)b * DIM + c0) * HW + n0;
    float ss = 0.f;
#pragma unroll
    for (int j = 0; j < 16; ++j) {
        int c = cb * 16 + j;
        float v = xp[(size_t)c * HW + ln];
        ss += v * v;
        xs[c * 65 + ln] = f2bs(v);
    }
    ps[cb][ln] = ss;
    __syncthreads();
    if (t < 64)
        rpart[((size_t)cy * NB + b) * HW + n0 + t] = ps[0][t] + ps[1][t] + ps[2][t] + ps[3][t];
    int n = t >> 2, ch = t & 3;
    alignas(16) short tmp[16];
#pragma unroll
    for (int i = 0; i < 16; ++i) tmp[i] = xs[(ch * 16 + i) * 65 + n];
    short* o = xT + ((size_t)b * HW + n0 + n) * DIM + c0 + ch * 16;
    *(bf16x8*)(o)     = *(bf16x8*)(tmp);
    *(bf16x8*)(o + 8) = *(bf16x8*)(tmp + 8);
}

// K2: GEMM (BM=384, BN=128, 12 waves). BK=32 double-buffer in 64KB STATIC LDS
//  (As 2x24K @0/@24576, Bs 2x8K @49152/@57344) -> 2 blocks/CU resident.
//  Per K-step: STAGE(next,buf^1) -> setprio(1) 16 MFMA setprio(0) -> vmcnt(0) -> raw barrier.
//  Epilogue (R8-proven, 0 conflicts): q-softmax -> qT; k,v -> exp/scale -> swizzled
//  LDS tiles -> PV MFMA -> pctx partials (+rowsum). r folded from rpart per-thread.
__global__ __launch_bounds__(768) void k_gemm(const short* __restrict__ w1b,
                                              const short* __restrict__ xT,
                                              const float* __restrict__ rpart,
                                              short* __restrict__ qT,
                                              float* __restrict__ pctx) {
    __shared__ __align__(16) char smem[65536];
    int nt = blockIdx.x, b = blockIdx.y;
    int t = threadIdx.x;
    int w = t >> 6, lane = t & 63;
    int wr = w >> 1, wc = w & 1;
    int lr = lane & 15, lg = lane >> 4;
    const f32x4 fz = {0.f, 0.f, 0.f, 0.f};
    f32x4 acc[4][4];
#pragma unroll
    for (int m = 0; m < 4; ++m)
#pragma unroll
        for (int n = 0; n < 4; ++n) acc[m][n] = fz;

    const short* Bg = xT + ((size_t)b * HW + nt * 128) * 256;

    auto STAGE = [&](int kt, int buf) {
        int kk = kt * 32;
        char* asb = smem + buf * 24576;
        char* bsb = smem + 49152 + buf * 8192;
#pragma unroll
        for (int is = 0; is < 2; ++is) {          // As: 384 rows x 32k bf16 = 24KB
            int o = is * 12288 + t * 16;
            int row = o >> 6;                     // 64B rows
            int js = ((o >> 4) & 3) ^ (row & 3);  // pre-swizzled source (T2)
            gld_lds16(w1b + (size_t)row * 256 + kk + js * 8, asb + o);
        }
        if (t < 512) {                            // Bs: 128 rows x 32k = 8KB
            int o = t * 16;
            int row = o >> 6;
            int js = ((o >> 4) & 3) ^ (row & 3);
            gld_lds16(Bg + (size_t)row * 256 + kk + js * 8, bsb + o);
        }
    };

    // prologue
    STAGE(0, 0);
    asm volatile("s_waitcnt vmcnt(0)" ::: "memory");
    __builtin_amdgcn_s_barrier();

#pragma unroll
    for (int kt = 0; kt < 8; ++kt) {
        int buf = kt & 1;
        if (kt < 7) STAGE(kt + 1, buf ^ 1);       // issue-early (T14)
        const char* asb = smem + buf * 24576;
        const char* bsb = smem + 49152 + buf * 8192;
        bf16x8 av[4], bv[4];
        __builtin_amdgcn_s_setprio(1);
#pragma unroll
        for (int m = 0; m < 4; ++m) {
            int row = wr * 64 + m * 16 + lr;
            av[m] = *(const bf16x8*)(asb + row * 64 + ((lg ^ (row & 3)) << 4));
        }
#pragma unroll
        for (int nf = 0; nf < 4; ++nf) {
            int row = wc * 64 + nf * 16 + lr;
            bv[nf] = *(const bf16x8*)(bsb + row * 64 + ((lg ^ (row & 3)) << 4));
        }
#pragma unroll
        for (int m = 0; m < 4; ++m)
#pragma unroll
            for (int nf = 0; nf < 4; ++nf)
                acc[m][nf] = __builtin_amdgcn_mfma_f32_16x16x32_bf16(av[m], bv[nf], acc[m][nf], 0, 0, 0);
        __builtin_amdgcn_s_setprio(0);
        asm volatile("s_waitcnt vmcnt(0)" ::: "memory");   // only next-tile loads in flight
        __builtin_amdgcn_s_barrier();
    }

    // r for this thread's 4 columns (k_rfin folded, rpart is L2-hot)
    int gcol0 = nt * 128 + wc * 64 + lr;
    float rv[4];
#pragma unroll
    for (int nf = 0; nf < 4; ++nf) {
        int col = gcol0 + nf * 16;
        float s = rpart[(size_t)b * HW + col] + rpart[(size_t)(16 + b) * HW + col]
                + rpart[(size_t)(32 + b) * HW + col] + rpart[(size_t)(48 + b) * HW + col];
        rv[nf] = 16.0f / fmaxf(sqrtf(s), 1e-12f);
    }

    // epilogue: all LDS free
    short* ekb = (short*)smem;              // [128 kd][128 col] bf16, 16B-chunk XOR swizzle
    short* vb  = (short*)(smem + 32768);    // [128 vd][128 col]

    if (wr < 2) {
        // q rows: softmax over d (32/head); head = wr*2 + a
#pragma unroll
        for (int nf = 0; nf < 4; ++nf) {
            int gcol = gcol0 + nf * 16;
#pragma unroll
            for (int a = 0; a < 2; ++a) {
                float v[8];
#pragma unroll
                for (int mm = 0; mm < 2; ++mm)
#pragma unroll
                    for (int q = 0; q < 4; ++q)
                        v[mm * 4 + q] = acc[2 * a + mm][nf][q] * rv[nf];
                float mx = v[0];
#pragma unroll
                for (int i = 1; i < 8; ++i) mx = fmaxf(mx, v[i]);
                mx = fmaxf(mx, __shfl_xor(mx, 16));
                mx = fmaxf(mx, __shfl_xor(mx, 32));
                float sum = 0.f;
#pragma unroll
                for (int i = 0; i < 8; ++i) { v[i] = __expf(v[i] - mx); sum += v[i]; }
                sum += __shfl_xor(sum, 16);
                sum += __shfl_xor(sum, 32);
                float inv = 0.17677669529663689f / sum;   // dhead^-0.5 / sum
                size_t base = ((size_t)b * HW + gcol) * 128 + (wr * 2 + a) * 32 + lg * 4;
#pragma unroll
                for (int mm = 0; mm < 2; ++mm) {
                    us4 pk;
#pragma unroll
                    for (int q = 0; q < 4; ++q)
                        pk[q] = (unsigned short)f2bs(v[mm * 4 + q] * inv);
                    *(us4*)(qT + base + mm * 16) = pk;
                }
            }
        }
    } else if (wr < 4) {
        // k rows -> ek = exp(k*r), swizzled tile
#pragma unroll
        for (int m = 0; m < 4; ++m)
#pragma unroll
            for (int nf = 0; nf < 4; ++nf)
#pragma unroll
                for (int q = 0; q < 4; ++q) {
                    int rloc = (wr - 2) * 64 + m * 16 + lg * 4 + q;
                    int col = wc * 64 + nf * 16 + lr;
                    int cs = ((((col >> 3) ^ (rloc & 15)) << 3) | (col & 7));
                    ekb[rloc * 128 + cs] = f2bs(__expf(acc[m][nf][q] * rv[nf]));
                }
    } else {
        // v rows -> swizzled tile
#pragma unroll
        for (int m = 0; m < 4; ++m)
#pragma unroll
            for (int nf = 0; nf < 4; ++nf)
#pragma unroll
                for (int q = 0; q < 4; ++q) {
                    int rloc = (wr - 4) * 64 + m * 16 + lg * 4 + q;
                    int col = wc * 64 + nf * 16 + lr;
                    int cs = ((((col >> 3) ^ (rloc & 15)) << 3) | (col & 7));
                    vb[rloc * 128 + cs] = f2bs(acc[m][nf][q] * rv[nf]);
                }
    }
    __syncthreads();
    if (w < 4) {
        // PV MFMA: ctx_h[d][e] = sum_n ek[h*32+d][n]*v[h*32+e][n]; wave w = head h
        int h = w;
        f32x4 c2[2][2];
        c2[0][0] = fz; c2[0][1] = fz; c2[1][0] = fz; c2[1][1] = fz;
#pragma unroll
        for (int ks = 0; ks < 4; ++ks) {
            int j = ks * 4 + lg;                 // 16B chunk 0..15
            bf16x8 a2[2], b2[2];
#pragma unroll
            for (int mm = 0; mm < 2; ++mm) {
                int row = h * 32 + mm * 16 + lr;
                a2[mm] = *(const bf16x8*)(ekb + row * 128 + ((j ^ (row & 15)) << 3));
            }
#pragma unroll
            for (int nn = 0; nn < 2; ++nn) {
                int row = h * 32 + nn * 16 + lr;
                b2[nn] = *(const bf16x8*)(vb + row * 128 + ((j ^ (row & 15)) << 3));
            }
#pragma unroll
            for (int mm = 0; mm < 2; ++mm)
#pragma unroll
                for (int nn = 0; nn < 2; ++nn)
                    c2[mm][nn] = __builtin_amdgcn_mfma_f32_16x16x32_bf16(a2[mm], b2[nn], c2[mm][nn], 0, 0, 0);
        }
        float* o = pctx + ((size_t)nt * 64 + b * 4 + h) * 1056;
#pragma unroll
        for (int mm = 0; mm < 2; ++mm)
#pragma unroll
            for (int nn = 0; nn < 2; ++nn)
#pragma unroll
                for (int qq = 0; qq < 4; ++qq) {
                    int d = mm * 16 + lg * 4 + qq;
                    int e = nn * 16 + lr;
                    o[d * 32 + e] = c2[mm][nn][qq];
                }
    } else if (w >= 8) {
        // rowsum partials over 128 cols of ekb
        int hd = (w - 8) * 32 + (lane & 31);
        int half = lane >> 5;
        float rs = 0.f;
#pragma unroll
        for (int blk = 0; blk < 8; ++blk) {
            int chunk = half * 8 + blk;
            bf16x8 e8 = *(const bf16x8*)(ekb + hd * 128 + ((chunk ^ (hd & 15)) << 3));
#pragma unroll
            for (int jj = 0; jj < 8; ++jj) rs += b2f(e8[jj]);
        }
        rs += __shfl_xor(rs, 32);
        if (lane < 32)
            pctx[((size_t)nt * 64 + b * 4 + (w - 8)) * 1056 + 1024 + (lane & 31)] = rs;
    }
}

// K3: reduce pctx over 32 chunks + mem-KV terms + normalize -> ctxn[bh][d*32+e]
__global__ __launch_bounds__(256) void k_red(const float* __restrict__ pctx,
                                             const float* __restrict__ memkv,
                                             float* __restrict__ ctxn) {
    int ds = blockIdx.x, bh = blockIdx.y;
    int t = threadIdx.x;
    int dd = t >> 5, ee = t & 31;
    int d = ds * 8 + dd;
    int h = bh & 3;
    __shared__ float rss[8];
    float s = 0.f;
#pragma unroll 8
    for (int c = 0; c < 32; ++c)
        s += pctx[((size_t)c * 64 + bh) * 1056 + d * 32 + ee];
    if (t < 8) {
        int d2 = ds * 8 + t;
        float rs = 0.f;
#pragma unroll 8
        for (int c = 0; c < 32; ++c)
            rs += pctx[((size_t)c * 64 + bh) * 1056 + 1024 + d2];
#pragma unroll
        for (int m2 = 0; m2 < MEM; ++m2) rs += __expf(memkv[(h * 32 + d2) * MEM + m2]);
        rss[t] = rs;
    }
    float mem = 0.f;
#pragma unroll
    for (int m2 = 0; m2 < MEM; ++m2)
        mem += __expf(memkv[(h * 32 + d) * MEM + m2]) * memkv[512 + (h * 32 + ee) * MEM + m2];
    __syncthreads();
    ctxn[(size_t)bh * 1024 + d * 32 + ee] = (s + mem) / rss[dd];
}

// K4: fold w_out: Mmat[b][o][hd] = sum_e wout[o][h*32+e] * ctxn[b*4+h][d][e]
__global__ __launch_bounds__(256) void k_M2(const float* __restrict__ ctxn,
                                            const float* __restrict__ wout,
                                            short* __restrict__ Mmat) {
    int og = blockIdx.x, b = blockIdx.y;
    __shared__ float ctx[4 * 33 * 33];
    __shared__ float wsw[32 * 136];
    int t = threadIdx.x;
#pragma unroll
    for (int j = 0; j < 16; ++j) {
        int e = t + j * 256;
        int h = e >> 10, dd = (e >> 5) & 31, ee = e & 31;
        ctx[h * 1089 + dd * 33 + ee] = ctxn[(size_t)(b * 4 + h) * 1024 + (e & 1023)];
    }
#pragma unroll
    for (int j = 0; j < 4; ++j) {
        int e4 = t + j * 256;
        int row = e4 >> 5, c = (e4 & 31) * 4;
        f32x4 w4 = *(const f32x4*)(wout + (size_t)(og * 32 + row) * HIDDEN + c);
        *(f32x4*)(wsw + row * 136 + (c >> 5) * 34 + (c & 31)) = w4;
    }
    __syncthreads();
    int ol = t >> 3, hg = t & 7;
    alignas(16) short out16[16];
#pragma unroll
    for (int ii = 0; ii < 16; ++ii) {
        int hd = hg * 16 + ii;
        int h = hd >> 5, dd = hd & 31;
        float s = 0.f;
#pragma unroll
        for (int e = 0; e < 32; ++e)
            s += wsw[ol * 136 + h * 34 + e] * ctx[h * 1089 + dd * 33 + e];
        out16[ii] = f2bs(s);
    }
    short* op = Mmat + ((size_t)(b * 256 + og * 32 + ol)) * 128 + hg * 16;
    *(bf16x8*)(op)     = *(bf16x8*)(out16);
    *(bf16x8*)(op + 8) = *(bf16x8*)(out16 + 8);
}

// K5: fused final GEMM + bias + column RMS-norm + g2 scale -> f32 out
__global__ __launch_bounds__(256) void k_out2(const short* __restrict__ Mmat,
                                              const short* __restrict__ qT,
                                              const float* __restrict__ bout,
                                              const float* __restrict__ g2,
                                              float* __restrict__ out) {
    int nt = blockIdx.x, b = blockIdx.y;
    __shared__ short As[256 * 64];
    __shared__ short Bs[64 * 64];
    __shared__ float sw[4][80];
    __shared__ float r2s[64];
    int t = threadIdx.x;
    int wave = t >> 6, lane = t & 63;
    int lr = lane & 15, lg = lane >> 4;
    const short* Ag = Mmat + (size_t)b * 256 * 128;
    const short* Bg = qT + ((size_t)b * HW + nt * 64) * 128;
    const f32x4 fz = {0.f, 0.f, 0.f, 0.f};
    f32x4 acc[4][4];
#pragma unroll
    for (int m = 0; m < 4; ++m)
#pragma unroll
        for (int n = 0; n < 4; ++n) acc[m][n] = fz;

    for (int kk = 0; kk < 128; kk += 64) {
        if (kk) __syncthreads();
#pragma unroll
        for (int is = 0; is < 8; ++is) {
            int o = is * 4096 + t * 16;
            int rr2 = o >> 7;
            int js = ((o >> 4) & 7) ^ (rr2 & 7);
            gld_lds16(Ag + (size_t)rr2 * 128 + kk + js * 8, (char*)As + o);
        }
#pragma unroll
        for (int is = 0; is < 2; ++is) {
            int o = is * 4096 + t * 16;
            int rr2 = o >> 7;
            int js = ((o >> 4) & 7) ^ (rr2 & 7);
            gld_lds16(Bg + (size_t)rr2 * 128 + kk + js * 8, (char*)Bs + o);
        }
        __syncthreads();
#pragma unroll
        for (int ks = 0; ks < 2; ++ks) {
            bf16x8 av[4], bv[4];
            int j = lg + 4 * ks;
#pragma unroll
            for (int m = 0; m < 4; ++m) {
                int row = wave * 64 + m * 16 + lr;
                av[m] = *(const bf16x8*)((const char*)As + row * 128 + ((j ^ (row & 7)) << 4));
            }
#pragma unroll
            for (int n = 0; n < 4; ++n) {
                int row = n * 16 + lr;
                bv[n] = *(const bf16x8*)((const char*)Bs + row * 128 + ((j ^ (row & 7)) << 4));
            }
#pragma unroll
            for (int m = 0; m < 4; ++m)
#pragma unroll
                for (int n = 0; n < 4; ++n)
                    acc[m][n] = __builtin_amdgcn_mfma_f32_16x16x32_bf16(av[m], bv[n], acc[m][n], 0, 0, 0);
        }
    }
    float bb[4][4], gg[4][4];
#pragma unroll
    for (int m = 0; m < 4; ++m)
#pragma unroll
        for (int q = 0; q < 4; ++q) {
            int row = wave * 64 + m * 16 + lg * 4 + q;
            bb[m][q] = bout[row];
            gg[m][q] = g2[row];
        }
    float ssn[4] = {0.f, 0.f, 0.f, 0.f};
#pragma unroll
    for (int n = 0; n < 4; ++n)
#pragma unroll
        for (int m = 0; m < 4; ++m)
#pragma unroll
            for (int q = 0; q < 4; ++q) {
                float val = acc[m][n][q] + bb[m][q];
                acc[m][n][q] = val;
                ssn[n] += val * val;
            }
#pragma unroll
    for (int n = 0; n < 4; ++n) {
        ssn[n] += __shfl_xor(ssn[n], 16);
        ssn[n] += __shfl_xor(ssn[n], 32);
    }
    if (lg == 0) {
#pragma unroll
        for (int n = 0; n < 4; ++n) sw[wave][n * 16 + lr] = ssn[n];
    }
    __syncthreads();
    if (t < 64) {
        float s = sw[0][t] + sw[1][t] + sw[2][t] + sw[3][t];
        r2s[t] = 16.0f / fmaxf(sqrtf(s), 1e-12f);
    }
    __syncthreads();
    float* op = out + (size_t)b * DIM * HW + nt * 64;
#pragma unroll
    for (int n = 0; n < 4; ++n) {
        float rc = r2s[n * 16 + lr];
#pragma unroll
        for (int m = 0; m < 4; ++m)
#pragma unroll
            for (int q = 0; q < 4; ++q) {
                int row = wave * 64 + m * 16 + lg * 4 + q;
                op[(size_t)row * HW + n * 16 + lr] = acc[m][n][q] * rc * gg[m][q];
            }
    }
}

extern "C" void kernel_launch(void* const* d_in, const int* in_sizes, int n_in,
                              void* d_out, int out_size, void* d_ws, size_t ws_size,
                              hipStream_t stream) {
    const float* x     = (const float*)d_in[0];
    const float* g1    = (const float*)d_in[1];
    const float* wqkv  = (const float*)d_in[2];
    const float* memkv = (const float*)d_in[3];
    const float* wout  = (const float*)d_in[4];
    const float* bout  = (const float*)d_in[5];
    const float* g2    = (const float*)d_in[6];
    float* out = (float*)d_out;
    char* ws = (char*)d_ws;

    short* w1b  = (short*)(ws + OFF_W1B);
    float* rpart= (float*)(ws + OFF_RP);
    float* pctx = (float*)(ws + OFF_PCTX);
    float* ctxn = (float*)(ws + OFF_CTXN);
    short* Mmat = (short*)(ws + OFF_M);
    short* qT   = (short*)(ws + OFF_QT);
    short* xT   = (short*)(ws + OFF_XT);

    k_tr<<<dim3(64, 4, NB), 256, 0, stream>>>(x, wqkv, g1, xT, rpart, w1b);
    k_gemm<<<dim3(32, NB), 768, 0, stream>>>(w1b, xT, rpart, qT, pctx);
    k_red<<<dim3(4, 64), 256, 0, stream>>>(pctx, memkv, ctxn);
    k_M2<<<dim3(8, NB), 256, 0, stream>>>(ctxn, wout, Mmat);
    k_out2<<<dim3(64, NB), 256, 0, stream>>>(Mmat, qT, bout, g2, out);
}

// Round 13
// 74.346 us; speedup vs baseline: 1.3714x; 1.0149x over previous
//
#include <hip/hip_runtime.h>
#include <hip/hip_bf16.h>

#define NB 16
#define DIM 256
#define HW 4096
#define HEADS 4
#define DHEAD 32
#define MEM 4
#define HIDDEN 128

typedef __hip_bfloat16 bf16;
typedef __attribute__((ext_vector_type(8))) short bf16x8;
typedef __attribute__((ext_vector_type(4))) float f32x4;
typedef __attribute__((ext_vector_type(4))) unsigned short us4;

#define AS1 __attribute__((address_space(1)))
#define AS3 __attribute__((address_space(3)))
#define WAIT_VM(N) asm volatile("s_waitcnt vmcnt(" #N ")" ::: "memory")

__device__ __forceinline__ void gld_lds16(const void* g, void* l) {
    __builtin_amdgcn_global_load_lds((const AS1 void*)g, (AS3 void*)l, 16, 0, 0);
}
__device__ __forceinline__ float b2f(short s) {
    union { unsigned int u; float f; } x; x.u = ((unsigned int)(unsigned short)s) << 16; return x.f;
}
__device__ __forceinline__ short f2bs(float f) {
    bf16 h = __float2bfloat16(f);
    return *reinterpret_cast<short*>(&h);
}

// ---- ws layout (bytes) ----
constexpr size_t OFF_W1B  = 0;                                    // 384*256 bf16
constexpr size_t OFF_RP   = OFF_W1B + 98304*2;                    // 4*65536 f32
constexpr size_t OFF_PCTX = OFF_RP + 4*65536*4;                   // 32*64*1056 f32
constexpr size_t OFF_CTXN = OFF_PCTX + (size_t)32*64*1056*4;      // 64*1024 f32
constexpr size_t OFF_M    = OFF_CTXN + (size_t)64*1024*4;         // 16*256*128 bf16
constexpr size_t OFF_QT   = OFF_M + (size_t)NB*DIM*HIDDEN*2;      // 16*4096*128 bf16
constexpr size_t OFF_XT   = OFF_QT + (size_t)NB*HW*HIDDEN*2;      // 16*4096*256 bf16

// K1: transpose x -> xT[b][n][c] (bf16) + partial sumsq per (b,n) (~HBM floor).
//     First 384 blocks additionally produce w1b = bf16(w_qkv * g1) (k_prep folded).
__global__ __launch_bounds__(256) void k_tr(const float* __restrict__ x,
                                            const float* __restrict__ wqkv,
                                            const float* __restrict__ g1,
                                            short* __restrict__ xT,
                                            float* __restrict__ rpart,
                                            short* __restrict__ w1b) {
    int t = threadIdx.x;
    int fid = blockIdx.x + (blockIdx.y << 6) + (blockIdx.z << 8);
    if (fid < 384) {
        int i = fid * 256 + t;
        w1b[i] = f2bs(wqkv[i] * g1[i & (DIM - 1)]);
    }
    int n0 = blockIdx.x * 64, cy = blockIdx.y, b = blockIdx.z;
    int c0 = cy * 64;
    __shared__ short xs[64 * 65];
    __shared__ float ps[4][64];
    int ln = t & 63, cb = t >> 6;
    const float* xp = x + ((size_t)b * DIM + c0) * HW + n0;
    float ss = 0.f;
#pragma unroll
    for (int j = 0; j < 16; ++j) {
        int c = cb * 16 + j;
        float v = xp[(size_t)c * HW + ln];
        ss += v * v;
        xs[c * 65 + ln] = f2bs(v);
    }
    ps[cb][ln] = ss;
    __syncthreads();
    if (t < 64)
        rpart[((size_t)cy * NB + b) * HW + n0 + t] = ps[0][t] + ps[1][t] + ps[2][t] + ps[3][t];
    int n = t >> 2, ch = t & 3;
    alignas(16) short tmp[16];
#pragma unroll
    for (int i = 0; i < 16; ++i) tmp[i] = xs[(ch * 16 + i) * 65 + n];
    short* o = xT + ((size_t)b * HW + n0 + n) * DIM + c0 + ch * 16;
    *(bf16x8*)(o)     = *(bf16x8*)(tmp);
    *(bf16x8*)(o + 8) = *(bf16x8*)(tmp + 8);
}

// K2: GEMM (BM=384, BN=128, 12 waves). BK=32 TRIPLE-buffer (96KB dynamic LDS),
//  2-deep counted-vmcnt pipeline (T3+T4): per step STAGE(kt+2) -> MFMA(kt) ->
//  wait vmcnt(3|2) (stage kt+2 stays in flight; kt+1 guaranteed landed) -> raw barrier.
//  Never drains to 0 in the main loop. Epilogue (R8-proven, 0 conflicts).
__global__ __launch_bounds__(768) void k_gemm(const short* __restrict__ w1b,
                                              const short* __restrict__ xT,
                                              const float* __restrict__ rpart,
                                              short* __restrict__ qT,
                                              float* __restrict__ pctx) {
    extern __shared__ __align__(16) char smem[];
    // As bufs @0/@24576/@49152 (24KB each); Bs bufs @73728/@81920/@90112 (8KB each)
    int nt = blockIdx.x, b = blockIdx.y;
    int t = threadIdx.x;
    int w = t >> 6, lane = t & 63;
    int wr = w >> 1, wc = w & 1;
    int lr = lane & 15, lg = lane >> 4;
    const f32x4 fz = {0.f, 0.f, 0.f, 0.f};
    f32x4 acc[4][4];
#pragma unroll
    for (int m = 0; m < 4; ++m)
#pragma unroll
        for (int n = 0; n < 4; ++n) acc[m][n] = fz;

    const short* Bg = xT + ((size_t)b * HW + nt * 128) * 256;

    auto STAGE = [&](int kt, int buf) {
        int kk = kt * 32;
        char* asb = smem + buf * 24576;
        char* bsb = smem + 73728 + buf * 8192;
#pragma unroll
        for (int is = 0; is < 2; ++is) {          // As: 384 rows x 32k bf16 = 24KB
            int o = is * 12288 + t * 16;
            int row = o >> 6;                     // 64B rows
            int js = ((o >> 4) & 3) ^ (row & 3);  // pre-swizzled source (T2)
            gld_lds16(w1b + (size_t)row * 256 + kk + js * 8, asb + o);
        }
        if (t < 512) {                            // Bs: 128 rows x 32k = 8KB (waves 0-7)
            int o = t * 16;
            int row = o >> 6;
            int js = ((o >> 4) & 3) ^ (row & 3);
            gld_lds16(Bg + (size_t)row * 256 + kk + js * 8, bsb + o);
        }
    };

    // prologue: fill 2 stages, wait only the first
    STAGE(0, 0);
    STAGE(1, 1);
    if (w < 8) { WAIT_VM(3); } else { WAIT_VM(2); }
    __builtin_amdgcn_s_barrier();

#pragma unroll
    for (int kt = 0; kt < 8; ++kt) {
        if (kt < 6) STAGE(kt + 2, (kt + 2) % 3);  // keep 2 stages in flight
        const char* asb = smem + (kt % 3) * 24576;
        const char* bsb = smem + 73728 + (kt % 3) * 8192;
        bf16x8 av[4], bv[4];
        __builtin_amdgcn_s_setprio(1);
#pragma unroll
        for (int m = 0; m < 4; ++m) {
            int row = wr * 64 + m * 16 + lr;
            av[m] = *(const bf16x8*)(asb + row * 64 + ((lg ^ (row & 3)) << 4));
        }
#pragma unroll
        for (int nf = 0; nf < 4; ++nf) {
            int row = wc * 64 + nf * 16 + lr;
            bv[nf] = *(const bf16x8*)(bsb + row * 64 + ((lg ^ (row & 3)) << 4));
        }
#pragma unroll
        for (int m = 0; m < 4; ++m)
#pragma unroll
            for (int nf = 0; nf < 4; ++nf)
                acc[m][nf] = __builtin_amdgcn_mfma_f32_16x16x32_bf16(av[m], bv[nf], acc[m][nf], 0, 0, 0);
        __builtin_amdgcn_s_setprio(0);
        if (kt < 6) {
            if (w < 8) { WAIT_VM(3); } else { WAIT_VM(2); }   // counted: kt+1 landed, kt+2 in flight
            __builtin_amdgcn_s_barrier();
        } else if (kt == 6) {
            WAIT_VM(0);                                        // last stage (7) must land
            __builtin_amdgcn_s_barrier();
        }
    }
    __syncthreads();   // all MFMA LDS reads done before epilogue reuses LDS

    // r for this thread's 4 columns (k_rfin folded, rpart is L2-hot)
    int gcol0 = nt * 128 + wc * 64 + lr;
    float rv[4];
#pragma unroll
    for (int nf = 0; nf < 4; ++nf) {
        int col = gcol0 + nf * 16;
        float s = rpart[(size_t)b * HW + col] + rpart[(size_t)(16 + b) * HW + col]
                + rpart[(size_t)(32 + b) * HW + col] + rpart[(size_t)(48 + b) * HW + col];
        rv[nf] = 16.0f / fmaxf(sqrtf(s), 1e-12f);
    }

    // epilogue: all LDS free
    short* ekb = (short*)smem;              // [128 kd][128 col] bf16, 16B-chunk XOR swizzle
    short* vb  = (short*)(smem + 32768);    // [128 vd][128 col]

    if (wr < 2) {
        // q rows: softmax over d (32/head); head = wr*2 + a
#pragma unroll
        for (int nf = 0; nf < 4; ++nf) {
            int gcol = gcol0 + nf * 16;
#pragma unroll
            for (int a = 0; a < 2; ++a) {
                float v[8];
#pragma unroll
                for (int mm = 0; mm < 2; ++mm)
#pragma unroll
                    for (int q = 0; q < 4; ++q)
                        v[mm * 4 + q] = acc[2 * a + mm][nf][q] * rv[nf];
                float mx = v[0];
#pragma unroll
                for (int i = 1; i < 8; ++i) mx = fmaxf(mx, v[i]);
                mx = fmaxf(mx, __shfl_xor(mx, 16));
                mx = fmaxf(mx, __shfl_xor(mx, 32));
                float sum = 0.f;
#pragma unroll
                for (int i = 0; i < 8; ++i) { v[i] = __expf(v[i] - mx); sum += v[i]; }
                sum += __shfl_xor(sum, 16);
                sum += __shfl_xor(sum, 32);
                float inv = 0.17677669529663689f / sum;   // dhead^-0.5 / sum
                size_t base = ((size_t)b * HW + gcol) * 128 + (wr * 2 + a) * 32 + lg * 4;
#pragma unroll
                for (int mm = 0; mm < 2; ++mm) {
                    us4 pk;
#pragma unroll
                    for (int q = 0; q < 4; ++q)
                        pk[q] = (unsigned short)f2bs(v[mm * 4 + q] * inv);
                    *(us4*)(qT + base + mm * 16) = pk;
                }
            }
        }
    } else if (wr < 4) {
        // k rows -> ek = exp(k*r), swizzled tile
#pragma unroll
        for (int m = 0; m < 4; ++m)
#pragma unroll
            for (int nf = 0; nf < 4; ++nf)
#pragma unroll
                for (int q = 0; q < 4; ++q) {
                    int rloc = (wr - 2) * 64 + m * 16 + lg * 4 + q;
                    int col = wc * 64 + nf * 16 + lr;
                    int cs = ((((col >> 3) ^ (rloc & 15)) << 3) | (col & 7));
                    ekb[rloc * 128 + cs] = f2bs(__expf(acc[m][nf][q] * rv[nf]));
                }
    } else {
        // v rows -> swizzled tile
#pragma unroll
        for (int m = 0; m < 4; ++m)
#pragma unroll
            for (int nf = 0; nf < 4; ++nf)
#pragma unroll
                for (int q = 0; q < 4; ++q) {
                    int rloc = (wr - 4) * 64 + m * 16 + lg * 4 + q;
                    int col = wc * 64 + nf * 16 + lr;
                    int cs = ((((col >> 3) ^ (rloc & 15)) << 3) | (col & 7));
                    vb[rloc * 128 + cs] = f2bs(acc[m][nf][q] * rv[nf]);
                }
    }
    __syncthreads();
    if (w < 4) {
        // PV MFMA: ctx_h[d][e] = sum_n ek[h*32+d][n]*v[h*32+e][n]; wave w = head h
        int h = w;
        f32x4 c2[2][2];
        c2[0][0] = fz; c2[0][1] = fz; c2[1][0] = fz; c2[1][1] = fz;
#pragma unroll
        for (int ks = 0; ks < 4; ++ks) {
            int j = ks * 4 + lg;                 // 16B chunk 0..15
            bf16x8 a2[2], b2[2];
#pragma unroll
            for (int mm = 0; mm < 2; ++mm) {
                int row = h * 32 + mm * 16 + lr;
                a2[mm] = *(const bf16x8*)(ekb + row * 128 + ((j ^ (row & 15)) << 3));
            }
#pragma unroll
            for (int nn = 0; nn < 2; ++nn) {
                int row = h * 32 + nn * 16 + lr;
                b2[nn] = *(const bf16x8*)(vb + row * 128 + ((j ^ (row & 15)) << 3));
            }
#pragma unroll
            for (int mm = 0; mm < 2; ++mm)
#pragma unroll
                for (int nn = 0; nn < 2; ++nn)
                    c2[mm][nn] = __builtin_amdgcn_mfma_f32_16x16x32_bf16(a2[mm], b2[nn], c2[mm][nn], 0, 0, 0);
        }
        float* o = pctx + ((size_t)nt * 64 + b * 4 + h) * 1056;
#pragma unroll
        for (int mm = 0; mm < 2; ++mm)
#pragma unroll
            for (int nn = 0; nn < 2; ++nn)
#pragma unroll
                for (int qq = 0; qq < 4; ++qq) {
                    int d = mm * 16 + lg * 4 + qq;
                    int e = nn * 16 + lr;
                    o[d * 32 + e] = c2[mm][nn][qq];
                }
    } else if (w >= 8) {
        // rowsum partials over 128 cols of ekb
        int hd = (w - 8) * 32 + (lane & 31);
        int half = lane >> 5;
        float rs = 0.f;
#pragma unroll
        for (int blk = 0; blk < 8; ++blk) {
            int chunk = half * 8 + blk;
            bf16x8 e8 = *(const bf16x8*)(ekb + hd * 128 + ((chunk ^ (hd & 15)) << 3));
#pragma unroll
            for (int jj = 0; jj < 8; ++jj) rs += b2f(e8[jj]);
        }
        rs += __shfl_xor(rs, 32);
        if (lane < 32)
            pctx[((size_t)nt * 64 + b * 4 + (w - 8)) * 1056 + 1024 + (lane & 31)] = rs;
    }
}

// K3: reduce pctx over 32 chunks + mem-KV terms + normalize -> ctxn[bh][d*32+e]
__global__ __launch_bounds__(256) void k_red(const float* __restrict__ pctx,
                                             const float* __restrict__ memkv,
                                             float* __restrict__ ctxn) {
    int ds = blockIdx.x, bh = blockIdx.y;
    int t = threadIdx.x;
    int dd = t >> 5, ee = t & 31;
    int d = ds * 8 + dd;
    int h = bh & 3;
    __shared__ float rss[8];
    float s = 0.f;
#pragma unroll 8
    for (int c = 0; c < 32; ++c)
        s += pctx[((size_t)c * 64 + bh) * 1056 + d * 32 + ee];
    if (t < 8) {
        int d2 = ds * 8 + t;
        float rs = 0.f;
#pragma unroll 8
        for (int c = 0; c < 32; ++c)
            rs += pctx[((size_t)c * 64 + bh) * 1056 + 1024 + d2];
#pragma unroll
        for (int m2 = 0; m2 < MEM; ++m2) rs += __expf(memkv[(h * 32 + d2) * MEM + m2]);
        rss[t] = rs;
    }
    float mem = 0.f;
#pragma unroll
    for (int m2 = 0; m2 < MEM; ++m2)
        mem += __expf(memkv[(h * 32 + d) * MEM + m2]) * memkv[512 + (h * 32 + ee) * MEM + m2];
    __syncthreads();
    ctxn[(size_t)bh * 1024 + d * 32 + ee] = (s + mem) / rss[dd];
}

// K4: fold w_out: Mmat[b][o][hd] = sum_e wout[o][h*32+e] * ctxn[b*4+h][d][e]
__global__ __launch_bounds__(256) void k_M2(const float* __restrict__ ctxn,
                                            const float* __restrict__ wout,
                                            short* __restrict__ Mmat) {
    int og = blockIdx.x, b = blockIdx.y;
    __shared__ float ctx[4 * 33 * 33];
    __shared__ float wsw[32 * 136];
    int t = threadIdx.x;
#pragma unroll
    for (int j = 0; j < 16; ++j) {
        int e = t + j * 256;
        int h = e >> 10, dd = (e >> 5) & 31, ee = e & 31;
        ctx[h * 1089 + dd * 33 + ee] = ctxn[(size_t)(b * 4 + h) * 1024 + (e & 1023)];
    }
#pragma unroll
    for (int j = 0; j < 4; ++j) {
        int e4 = t + j * 256;
        int row = e4 >> 5, c = (e4 & 31) * 4;
        f32x4 w4 = *(const f32x4*)(wout + (size_t)(og * 32 + row) * HIDDEN + c);
        *(f32x4*)(wsw + row * 136 + (c >> 5) * 34 + (c & 31)) = w4;
    }
    __syncthreads();
    int ol = t >> 3, hg = t & 7;
    alignas(16) short out16[16];
#pragma unroll
    for (int ii = 0; ii < 16; ++ii) {
        int hd = hg * 16 + ii;
        int h = hd >> 5, dd = hd & 31;
        float s = 0.f;
#pragma unroll
        for (int e = 0; e < 32; ++e)
            s += wsw[ol * 136 + h * 34 + e] * ctx[h * 1089 + dd * 33 + e];
        out16[ii] = f2bs(s);
    }
    short* op = Mmat + ((size_t)(b * 256 + og * 32 + ol)) * 128 + hg * 16;
    *(bf16x8*)(op)     = *(bf16x8*)(out16);
    *(bf16x8*)(op + 8) = *(bf16x8*)(out16 + 8);
}

// K5: fused final GEMM + bias + column RMS-norm + g2 scale -> f32 out
__global__ __launch_bounds__(256) void k_out2(const short* __restrict__ Mmat,
                                              const short* __restrict__ qT,
                                              const float* __restrict__ bout,
                                              const float* __restrict__ g2,
                                              float* __restrict__ out) {
    int nt = blockIdx.x, b = blockIdx.y;
    __shared__ short As[256 * 64];
    __shared__ short Bs[64 * 64];
    __shared__ float sw[4][80];
    __shared__ float r2s[64];
    int t = threadIdx.x;
    int wave = t >> 6, lane = t & 63;
    int lr = lane & 15, lg = lane >> 4;
    const short* Ag = Mmat + (size_t)b * 256 * 128;
    const short* Bg = qT + ((size_t)b * HW + nt * 64) * 128;
    const f32x4 fz = {0.f, 0.f, 0.f, 0.f};
    f32x4 acc[4][4];
#pragma unroll
    for (int m = 0; m < 4; ++m)
#pragma unroll
        for (int n = 0; n < 4; ++n) acc[m][n] = fz;

    for (int kk = 0; kk < 128; kk += 64) {
        if (kk) __syncthreads();
#pragma unroll
        for (int is = 0; is < 8; ++is) {
            int o = is * 4096 + t * 16;
            int rr2 = o >> 7;
            int js = ((o >> 4) & 7) ^ (rr2 & 7);
            gld_lds16(Ag + (size_t)rr2 * 128 + kk + js * 8, (char*)As + o);
        }
#pragma unroll
        for (int is = 0; is < 2; ++is) {
            int o = is * 4096 + t * 16;
            int rr2 = o >> 7;
            int js = ((o >> 4) & 7) ^ (rr2 & 7);
            gld_lds16(Bg + (size_t)rr2 * 128 + kk + js * 8, (char*)Bs + o);
        }
        __syncthreads();
#pragma unroll
        for (int ks = 0; ks < 2; ++ks) {
            bf16x8 av[4], bv[4];
            int j = lg + 4 * ks;
#pragma unroll
            for (int m = 0; m < 4; ++m) {
                int row = wave * 64 + m * 16 + lr;
                av[m] = *(const bf16x8*)((const char*)As + row * 128 + ((j ^ (row & 7)) << 4));
            }
#pragma unroll
            for (int n = 0; n < 4; ++n) {
                int row = n * 16 + lr;
                bv[n] = *(const bf16x8*)((const char*)Bs + row * 128 + ((j ^ (row & 7)) << 4));
            }
#pragma unroll
            for (int m = 0; m < 4; ++m)
#pragma unroll
                for (int n = 0; n < 4; ++n)
                    acc[m][n] = __builtin_amdgcn_mfma_f32_16x16x32_bf16(av[m], bv[n], acc[m][n], 0, 0, 0);
        }
    }
    float bb[4][4], gg[4][4];
#pragma unroll
    for (int m = 0; m < 4; ++m)
#pragma unroll
        for (int q = 0; q < 4; ++q) {
            int row = wave * 64 + m * 16 + lg * 4 + q;
            bb[m][q] = bout[row];
            gg[m][q] = g2[row];
        }
    float ssn[4] = {0.f, 0.f, 0.f, 0.f};
#pragma unroll
    for (int n = 0; n < 4; ++n)
#pragma unroll
        for (int m = 0; m < 4; ++m)
#pragma unroll
            for (int q = 0; q < 4; ++q) {
                float val = acc[m][n][q] + bb[m][q];
                acc[m][n][q] = val;
                ssn[n] += val * val;
            }
#pragma unroll
    for (int n = 0; n < 4; ++n) {
        ssn[n] += __shfl_xor(ssn[n], 16);
        ssn[n] += __shfl_xor(ssn[n], 32);
    }
    if (lg == 0) {
#pragma unroll
        for (int n = 0; n < 4; ++n) sw[wave][n * 16 + lr] = ssn[n];
    }
    __syncthreads();
    if (t < 64) {
        float s = sw[0][t] + sw[1][t] + sw[2][t] + sw[3][t];
        r2s[t] = 16.0f / fmaxf(sqrtf(s), 1e-12f);
    }
    __syncthreads();
    float* op = out + (size_t)b * DIM * HW + nt * 64;
#pragma unroll
    for (int n = 0; n < 4; ++n) {
        float rc = r2s[n * 16 + lr];
#pragma unroll
        for (int m = 0; m < 4; ++m)
#pragma unroll
            for (int q = 0; q < 4; ++q) {
                int row = wave * 64 + m * 16 + lg * 4 + q;
                op[(size_t)row * HW + n * 16 + lr] = acc[m][n][q] * rc * gg[m][q];
            }
    }
}

extern "C" void kernel_launch(void* const* d_in, const int* in_sizes, int n_in,
                              void* d_out, int out_size, void* d_ws, size_t ws_size,
                              hipStream_t stream) {
    const float* x     = (const float*)d_in[0];
    const float* g1    = (const float*)d_in[1];
    const float* wqkv  = (const float*)d_in[2];
    const float* memkv = (const float*)d_in[3];
    const float* wout  = (const float*)d_in[4];
    const float* bout  = (const float*)d_in[5];
    const float* g2    = (const float*)d_in[6];
    float* out = (float*)d_out;
    char* ws = (char*)d_ws;

    short* w1b  = (short*)(ws + OFF_W1B);
    float* rpart= (float*)(ws + OFF_RP);
    float* pctx = (float*)(ws + OFF_PCTX);
    float* ctxn = (float*)(ws + OFF_CTXN);
    short* Mmat = (short*)(ws + OFF_M);
    short* qT   = (short*)(ws + OFF_QT);
    short* xT   = (short*)(ws + OFF_XT);

    // allow 96KB dynamic LDS for k_gemm (non-stream op; deterministic each call)
    hipFuncSetAttribute((const void*)k_gemm,
                        hipFuncAttributeMaxDynamicSharedMemorySize, 98304);

    k_tr<<<dim3(64, 4, NB), 256, 0, stream>>>(x, wqkv, g1, xT, rpart, w1b);
    k_gemm<<<dim3(32, NB), 768, 98304, stream>>>(w1b, xT, rpart, qT, pctx);
    k_red<<<dim3(4, 64), 256, 0, stream>>>(pctx, memkv, ctxn);
    k_M2<<<dim3(8, NB), 256, 0, stream>>>(ctxn, wout, Mmat);
    k_out2<<<dim3(64, NB), 256, 0, stream>>>(Mmat, qT, bout, g2, out);
}